// Round 7
// baseline (1794.440 us; speedup 1.0000x reference)
//
#include <hip/hip_runtime.h>

typedef unsigned int uint;
typedef unsigned short ushort;
typedef __bf16 bf16x8_t __attribute__((ext_vector_type(8)));
typedef float f32x4_t __attribute__((ext_vector_type(4)));

// ---------- helpers ----------
__device__ __forceinline__ ushort f2b(float f) {
    uint u = __builtin_bit_cast(uint, f);
    u += 0x7fffu + ((u >> 16) & 1u);   // RNE
    return (ushort)(u >> 16);
}
__device__ __forceinline__ float b2f(ushort h) {
    return __builtin_bit_cast(float, (uint)h << 16);
}
__device__ __forceinline__ float sigm(float v) { return 1.f / (1.f + __expf(-v)); }
__device__ __forceinline__ float tanh_(float v) {
    v = fmaxf(-15.f, fminf(15.f, v));
    float e = __expf(2.f * v);
    return (e - 1.f) / (e + 1.f);
}

// ---------- coherent (cross-XCD) primitives ----------
__device__ __forceinline__ uint ld_cg_u32(const uint* p) {
    uint r;
    asm volatile("global_load_dword %0, %1, off sc0 sc1\n\ts_waitcnt vmcnt(0)"
                 : "=v"(r) : "v"(p) : "memory");
    return r;
}
__device__ __forceinline__ void st_cg_u16(ushort* p, uint v) {
    asm volatile("global_store_short %0, %1, off sc0 sc1" :: "v"(p), "v"(v) : "memory");
}
__device__ __forceinline__ bf16x8_t u2b(uint4 u) { return __builtin_bit_cast(bf16x8_t, u); }

// counter-based handshake: producers atomicAdd after their wave's stores drain;
// consumer wave's lane 0 polls one padded counter (64B apart).
__device__ __forceinline__ void cnt_wait(const uint* c, int lane) {
    if (lane == 0) {
        while (ld_cg_u32(c) < 64u) __builtin_amdgcn_s_sleep(1);
    }
    __builtin_amdgcn_sched_barrier(0);   // keep subsequent loads after the poll
}
__device__ __forceinline__ void cnt_arrive(uint* c, int lane) {
    asm volatile("s_waitcnt vmcnt(0)" ::: "memory");   // this wave's sc0sc1 stores at MALL
    if (lane == 0) atomicAdd(c, 1u);
}
// counter index helpers (each counter padded to 16 uints = 64B)
__device__ __forceinline__ uint* CG(uint* c, int t, int q) { return c + (((t << 2) + q) << 4); }
__device__ __forceinline__ uint* CA(uint* c, int t, int r, int q) { return c + ((256 + (t << 3) + (r << 2) + q) << 4); }
__device__ __forceinline__ uint* CB(uint* c, int t, int r, int q) { return c + ((768 + (t << 3) + (r << 2) + q) << 4); }

#define SMEM_BYTES 36864
union U8 { ushort h[8]; uint4 v; };

// ---------- generic bf16 GEMM body: C = A @ B^T (+epilogue) ----------
// EPI: 0 f32 out +bias; 1 bf16 plain; 2 bf16 +bias
template<int BN, int EPI, bool AF32>
__device__ __forceinline__ void gemm_body(
    int bx, int by, const void* Av, int lda,
    const ushort* Bp, int ldb, int K,
    void* Ov, int ldo, const float* bias, char* smem)
{
    constexpr int LDW = 72;
    ushort* As = (ushort*)smem;                     // [128][72]
    ushort* Bs = (ushort*)(smem + 128 * LDW * 2);   // [BN][72]
    const int tid = threadIdx.x, lane = tid & 63, wid = tid >> 6;
    constexpr int WC = (BN == 128) ? 2 : 1;
    constexpr int WR = 4 / WC;
    constexpr int WROWS = 128 / WR;
    constexpr int WCOLS = BN / WC;
    constexpr int MI = WROWS / 16, NI = WCOLS / 16;
    const int wr = (WC == 2) ? (wid >> 1) : wid;
    const int wc = (WC == 2) ? (wid & 1) : 0;
    const int row0 = by * 128, col0 = bx * BN;

    f32x4_t acc[MI][NI];
#pragma unroll
    for (int i = 0; i < MI; i++)
#pragma unroll
        for (int j = 0; j < NI; j++) acc[i][j] = (f32x4_t){0.f, 0.f, 0.f, 0.f};

    for (int k0 = 0; k0 < K; k0 += 64) {
        __syncthreads();
#pragma unroll
        for (int cc = 0; cc < 4; cc++) {
            int chunk = tid + cc * 256;
            int r = chunk >> 3, c8 = chunk & 7;
            uint4 val;
            if constexpr (AF32) {
                const float* Af = (const float*)Av + (size_t)(row0 + r) * lda + k0 + c8 * 8;
                float4 v0 = ((const float4*)Af)[0];
                float4 v1 = ((const float4*)Af)[1];
                U8 u;
                u.h[0] = f2b(v0.x); u.h[1] = f2b(v0.y); u.h[2] = f2b(v0.z); u.h[3] = f2b(v0.w);
                u.h[4] = f2b(v1.x); u.h[5] = f2b(v1.y); u.h[6] = f2b(v1.z); u.h[7] = f2b(v1.w);
                val = u.v;
            } else {
                val = *(const uint4*)((const ushort*)Av + (size_t)(row0 + r) * lda + k0 + c8 * 8);
            }
            *(uint4*)&As[r * LDW + c8 * 8] = val;
        }
#pragma unroll
        for (int cc = 0; cc < BN / 32; cc++) {
            int chunk = tid + cc * 256;
            int r = chunk >> 3, c8 = chunk & 7;
            uint4 val = *(const uint4*)(Bp + (size_t)(col0 + r) * ldb + k0 + c8 * 8);
            *(uint4*)&Bs[r * LDW + c8 * 8] = val;
        }
        __syncthreads();
#pragma unroll
        for (int kk = 0; kk < 64; kk += 32) {
            int ko = kk + ((lane >> 4) << 3);
            bf16x8_t af[MI], bf[NI];
#pragma unroll
            for (int mi = 0; mi < MI; mi++)
                af[mi] = *(const bf16x8_t*)&As[(wr * WROWS + mi * 16 + (lane & 15)) * LDW + ko];
#pragma unroll
            for (int ni = 0; ni < NI; ni++)
                bf[ni] = *(const bf16x8_t*)&Bs[(wc * WCOLS + ni * 16 + (lane & 15)) * LDW + ko];
#pragma unroll
            for (int mi = 0; mi < MI; mi++)
#pragma unroll
                for (int ni = 0; ni < NI; ni++)
                    acc[mi][ni] = __builtin_amdgcn_mfma_f32_16x16x32_bf16(af[mi], bf[ni], acc[mi][ni], 0, 0, 0);
        }
    }
#pragma unroll
    for (int mi = 0; mi < MI; mi++) {
#pragma unroll
        for (int ni = 0; ni < NI; ni++) {
            int gcol = col0 + wc * WCOLS + ni * 16 + (lane & 15);
#pragma unroll
            for (int i = 0; i < 4; i++) {
                int grow = row0 + wr * WROWS + mi * 16 + ((lane >> 4) << 2) + i;
                float v = acc[mi][ni][i];
                if constexpr (EPI == 0) {
                    ((float*)Ov)[(size_t)grow * ldo + gcol] = v + bias[gcol];
                } else if constexpr (EPI == 1) {
                    ((ushort*)Ov)[(size_t)grow * ldo + gcol] = f2b(v);
                } else {
                    ((ushort*)Ov)[(size_t)grow * ldo + gcol] = f2b(v + bias[gcol]);
                }
            }
        }
    }
}

template<int BN, int EPI, bool AF32>
__global__ __launch_bounds__(256) void gemm_k(
    const void* A, int lda, const ushort* B, int ldb, int K,
    void* O, int ldo, const float* bias)
{
    __shared__ char smem[SMEM_BYTES];
    gemm_body<BN, EPI, AF32>(blockIdx.x, blockIdx.y, A, lda, B, ldb, K, O, ldo, bias, smem);
}

// ---------- GRU role: 64 WGs, each owns 16 h-cols x 128 rows ----------
// hb is t-indexed: hb + t*131072 (bf16 [128][1024] per step).
__device__ void role_gru(int cb, const ushort* __restrict__ whhb, ushort* hb,
                         const ushort* __restrict__ gi, const float* masks,
                         const float* b_ih, const float* b_hh, const float* hxs_g,
                         float* out, uint* cnt, char* lds)
{
    const int tid = threadIdx.x, lane = tid & 63, w = tid >> 6;
    const int colL = cb * 16 + (lane & 15);
    const int kw = w * 256;                 // K-quarter per wave
    const int kl = (lane >> 4) << 3;
    const int q = cb >> 4;

    bf16x8_t bw[3][8];                      // w_hh frags, resident all 64 steps
#pragma unroll
    for (int g = 0; g < 3; g++)
#pragma unroll
        for (int ks = 0; ks < 8; ks++)
            bw[g][ks] = *(const bf16x8_t*)(whhb + (size_t)(g * 1024 + colL) * 1024 + kw + ks * 32 + kl);

    const float bihr = b_ih[colL], bihz = b_ih[1024 + colL], bihn = b_ih[2048 + colL];
    const float bhhr = b_hh[colL], bhhz = b_hh[1024 + colL], bhhn = b_hh[2048 + colL];

    f32x4_t hown[2];                        // own h slice
#pragma unroll
    for (int j = 0; j < 2; j++)
#pragma unroll
        for (int i = 0; i < 4; i++)
            hown[j][i] = hxs_g[(size_t)((2 * w + j) * 16 + ((lane >> 4) << 2) + i) * 1024 + colL];

    for (int t = 0; t < 64; t++) {
        // prefetch epilogue operands BEFORE the wait (overlaps poll latency)
        float mc[2][4], mn[2][4], g0p[2][4], g1p[2][4], g2p[2][4];
#pragma unroll
        for (int j = 0; j < 2; j++) {
            const int rt = 2 * w + j;
#pragma unroll
            for (int i = 0; i < 4; i++) {
                const int row = rt * 16 + ((lane >> 4) << 2) + i;
                mc[j][i] = masks[t * 128 + row];
                mn[j][i] = (t < 63) ? masks[(t + 1) * 128 + row] : 0.f;
                const size_t gib = (size_t)(t * 128 + row) * 3072;
                g0p[j][i] = b2f(gi[gib + colL]);
                g1p[j][i] = b2f(gi[gib + 1024 + colL]);
                g2p[j][i] = b2f(gi[gib + 2048 + colL]);
            }
        }
        if (t) cnt_wait(CG(cnt, t - 1, w), lane);   // wave-granular: only this wave's K-slice producers
        const ushort* base = hb + (size_t)t * 131072 + (size_t)(lane & 15) * 1024 + kw + kl;
        f32x4_t acc[3][8];
#pragma unroll
        for (int g = 0; g < 3; g++)
#pragma unroll
            for (int rt = 0; rt < 8; rt++) acc[g][rt] = (f32x4_t){0.f, 0.f, 0.f, 0.f};
#pragma unroll
        for (int ks = 0; ks < 8; ks++) {
            bf16x8_t af[8];
#pragma unroll
            for (int rt = 0; rt < 8; rt++)
                af[rt] = *(const bf16x8_t*)(base + (size_t)rt * 16384 + ks * 32);
#pragma unroll
            for (int g = 0; g < 3; g++)
#pragma unroll
                for (int rt = 0; rt < 8; rt++)
                    acc[g][rt] = __builtin_amdgcn_mfma_f32_16x16x32_bf16(af[rt], bw[g][ks], acc[g][rt], 0, 0, 0);
        }
        __syncthreads();   // all waves done reading previous iteration's LDS slots
#pragma unroll
        for (int g = 0; g < 3; g++)
#pragma unroll
            for (int rt = 0; rt < 8; rt++)
                *(f32x4_t*)(lds + ((size_t)(w * 24 + g * 8 + rt) * 64 + lane) * 16) = acc[g][rt];
        __syncthreads();
#pragma unroll
        for (int j = 0; j < 2; j++) {
            const int rt = 2 * w + j;
            f32x4_t sg[3];
#pragma unroll
            for (int g = 0; g < 3; g++) {
                sg[g] = (f32x4_t){0.f, 0.f, 0.f, 0.f};
#pragma unroll
                for (int ww = 0; ww < 4; ww++)
                    sg[g] += *(const f32x4_t*)(lds + ((size_t)(ww * 24 + g * 8 + rt) * 64 + lane) * 16);
            }
#pragma unroll
            for (int i = 0; i < 4; i++) {
                const int row = rt * 16 + ((lane >> 4) << 2) + i;
                const float h0 = hown[j][i] * mc[j][i];
                const float rv = sigm(g0p[j][i] + bihr + bhhr + sg[0][i]);
                const float zv = sigm(g1p[j][i] + bihz + bhhz + sg[1][i]);
                const float nv = tanh_(g2p[j][i] + bihn + rv * (sg[2][i] + bhhn));
                const float hnew = (1.f - zv) * nv + zv * h0;
                out[(size_t)(t * 128 + row) * 1024 + colL] = hnew;
                hown[j][i] = hnew;
                if (t < 63)
                    st_cg_u16(hb + (size_t)(t + 1) * 131072 + (size_t)row * 1024 + colL,
                              (uint)f2b(hnew * mn[j][i]));
            }
        }
        cnt_arrive(CG(cnt, t, q), lane);    // per-wave publish
    }
}

// ---------- P role: 128 WGs, phase A (d1) then phase B (d2) per step ----------
// d1r t-indexed (stride 262144 ushorts), d2r t-indexed (stride 131072 ushorts).
__device__ void role_p(int p, const ushort* __restrict__ Wcb, const ushort* __restrict__ w1h1b,
                       const ushort* __restrict__ hp1b, const ushort* __restrict__ w2b,
                       const ushort* __restrict__ d1pre, const float* masks, const float* cvec,
                       const float* p_b2, ushort* d1r, ushort* d2r, uint* cnt, char* lds)
{
    const int tid = threadIdx.x, lane = tid & 63, w = tid >> 6;
    const int rowg = p >> 6, colg = p & 63;
    const int rA0 = rowg * 64, cA0 = colg * 32;   // phase A: 64 rows x 32 d1-cols, K=1024
    const int rB0 = rowg * 64, cB0 = colg * 16;   // phase B: 64 rows x 16 d2-cols, K=2048
    const int kwA = w * 256, kwB = w * 512, kl = (lane >> 4) << 3;
    const int qp = colg >> 4;

    bf16x8_t wcF[2][8];                     // Wc slice, resident
#pragma unroll
    for (int ct = 0; ct < 2; ct++)
#pragma unroll
        for (int ks = 0; ks < 8; ks++)
            wcF[ct][ks] = *(const bf16x8_t*)(Wcb + (size_t)(cA0 + ct * 16 + (lane & 15)) * 1024 + kwA + ks * 32 + kl);
    bf16x8_t w2F[16];                       // w2 slice, resident
#pragma unroll
    for (int ks = 0; ks < 16; ks++)
        w2F[ks] = *(const bf16x8_t*)(w2b + (size_t)(cB0 + (lane & 15)) * 2048 + kwB + ks * 32 + kl);
    const float cv0 = cvec[cA0 + (lane & 15)], cv1 = cvec[cA0 + 16 + (lane & 15)];
    const float pb = p_b2[cB0 + (lane & 15)];

    for (int t = 0; t < 64; t++) {
        // prefetch epilogue operands BEFORE the wait
        float mA[4], preA[2][4];
#pragma unroll
        for (int i = 0; i < 4; i++) {
            const int row = rA0 + w * 16 + ((lane >> 4) << 2) + i;
            mA[i] = masks[t * 128 + row];
            preA[0][i] = b2f(d1pre[(size_t)(t * 128 + row) * 2048 + cA0 + (lane & 15)]);
            preA[1][i] = b2f(d1pre[(size_t)(t * 128 + row) * 2048 + cA0 + 16 + (lane & 15)]);
        }
        if (t) cnt_wait(CB(cnt, t - 1, rowg, w), lane);
        // ---- phase A: d1 = relu(d1pre + m*(Wc@d2prev + cvec))  (t=0: m*(W1h1@hp1)) ----
        f32x4_t accA[2][4];
#pragma unroll
        for (int ct = 0; ct < 2; ct++)
#pragma unroll
            for (int rt = 0; rt < 4; rt++) accA[ct][rt] = (f32x4_t){0.f, 0.f, 0.f, 0.f};
        if (t == 0) {
#pragma unroll
            for (int ks = 0; ks < 8; ks++) {
                bf16x8_t af[4], b0[2];
#pragma unroll
                for (int ct = 0; ct < 2; ct++)
                    b0[ct] = *(const bf16x8_t*)(w1h1b + (size_t)(cA0 + ct * 16 + (lane & 15)) * 1024 + kwA + ks * 32 + kl);
#pragma unroll
                for (int rt = 0; rt < 4; rt++)
                    af[rt] = *(const bf16x8_t*)(hp1b + (size_t)(rA0 + rt * 16 + (lane & 15)) * 1024 + kwA + ks * 32 + kl);
#pragma unroll
                for (int ct = 0; ct < 2; ct++)
#pragma unroll
                    for (int rt = 0; rt < 4; rt++)
                        accA[ct][rt] = __builtin_amdgcn_mfma_f32_16x16x32_bf16(af[rt], b0[ct], accA[ct][rt], 0, 0, 0);
            }
        } else {
            const ushort* Ab = d2r + (size_t)(t - 1) * 131072 + (size_t)(rA0 + (lane & 15)) * 1024 + kwA + kl;
#pragma unroll
            for (int ks = 0; ks < 8; ks++) {
                bf16x8_t af[4];
#pragma unroll
                for (int rt = 0; rt < 4; rt++)
                    af[rt] = *(const bf16x8_t*)(Ab + (size_t)rt * 16384 + ks * 32);
#pragma unroll
                for (int ct = 0; ct < 2; ct++)
#pragma unroll
                    for (int rt = 0; rt < 4; rt++)
                        accA[ct][rt] = __builtin_amdgcn_mfma_f32_16x16x32_bf16(af[rt], wcF[ct][ks], accA[ct][rt], 0, 0, 0);
            }
        }
        __syncthreads();   // previous phase's LDS-slot reads complete
#pragma unroll
        for (int ct = 0; ct < 2; ct++)
#pragma unroll
            for (int rt = 0; rt < 4; rt++)
                *(f32x4_t*)(lds + ((size_t)(w * 8 + ct * 4 + rt) * 64 + lane) * 16) = accA[ct][rt];
        __syncthreads();
#pragma unroll
        for (int ct = 0; ct < 2; ct++) {
            f32x4_t s = (f32x4_t){0.f, 0.f, 0.f, 0.f};
#pragma unroll
            for (int ww = 0; ww < 4; ww++)
                s += *(const f32x4_t*)(lds + ((size_t)(ww * 8 + ct * 4 + w) * 64 + lane) * 16);
            const int col = cA0 + ct * 16 + (lane & 15);
            const float cvt = (t == 0) ? 0.f : (ct ? cv1 : cv0);
#pragma unroll
            for (int i = 0; i < 4; i++) {
                const int row = rA0 + w * 16 + ((lane >> 4) << 2) + i;
                float f = preA[ct][i] + mA[i] * (s[i] + cvt);
                st_cg_u16(d1r + (size_t)t * 262144 + (size_t)row * 2048 + col, (uint)f2b(f > 0.f ? f : 0.f));
            }
        }
        cnt_arrive(CA(cnt, t, rowg, qp), lane);
        cnt_wait(CA(cnt, t, rowg, w), lane);      // this wave's d1 K-slice ready
        // ---- phase B: d2 = relu(d1 @ w2^T + b2) ----
        f32x4_t accB[4];
#pragma unroll
        for (int rt = 0; rt < 4; rt++) accB[rt] = (f32x4_t){0.f, 0.f, 0.f, 0.f};
        {
            const ushort* Bb = d1r + (size_t)t * 262144 + (size_t)(rB0 + (lane & 15)) * 2048 + kwB + kl;
#pragma unroll
            for (int ks = 0; ks < 16; ks++) {
                bf16x8_t af[4];
#pragma unroll
                for (int rt = 0; rt < 4; rt++)
                    af[rt] = *(const bf16x8_t*)(Bb + (size_t)rt * 32768 + ks * 32);
#pragma unroll
                for (int rt = 0; rt < 4; rt++)
                    accB[rt] = __builtin_amdgcn_mfma_f32_16x16x32_bf16(af[rt], w2F[ks], accB[rt], 0, 0, 0);
            }
        }
        __syncthreads();   // phase A slot reads complete
#pragma unroll
        for (int rt = 0; rt < 4; rt++)
            *(f32x4_t*)(lds + ((size_t)(w * 4 + rt) * 64 + lane) * 16) = accB[rt];
        __syncthreads();
        {
            f32x4_t s = (f32x4_t){0.f, 0.f, 0.f, 0.f};
#pragma unroll
            for (int ww = 0; ww < 4; ww++)
                s += *(const f32x4_t*)(lds + ((size_t)(ww * 4 + w) * 64 + lane) * 16);
            const int col = cB0 + (lane & 15);
#pragma unroll
            for (int i = 0; i < 4; i++) {
                const int row = rB0 + w * 16 + ((lane >> 4) << 2) + i;
                float f = s[i] + pb;
                st_cg_u16(d2r + (size_t)t * 131072 + (size_t)row * 1024 + col, (uint)f2b(f > 0.f ? f : 0.f));
            }
        }
        cnt_arrive(CB(cnt, t, rowg, qp), lane);
    }
}

__global__ __launch_bounds__(256, 1) void persist_k(
    const ushort* whhb, const ushort* Wcb, const ushort* w1h1b, const ushort* w2b,
    const ushort* gi, const ushort* d1pre, const ushort* hp1b,
    ushort* hb, ushort* d1r, ushort* d2r,
    const float* masks, const float* b_ih, const float* b_hh,
    const float* cvec, const float* p_b2, const float* hxs_g,
    float* out, uint* cnt)
{
    __shared__ __align__(16) char lds[98304];
    const int wg = blockIdx.x;
    if (wg < 64) role_gru(wg, whhb, hb, gi, masks, b_ih, b_hh, hxs_g, out, cnt, lds);
    else         role_p(wg - 64, Wcb, w1h1b, hp1b, w2b, d1pre, masks, cvec, p_b2, d1r, d2r, cnt, lds);
}

// ---------- prep kernels ----------
__global__ void prep_w(const float* w_ih, const float* w_hh, const float* p_w1,
                       const float* p_w2, const float* mu_w, const float* lv_w,
                       ushort* wihb, ushort* whhb, ushort* w2b, ushort* muwb,
                       ushort* lvwb, ushort* muwTb, ushort* w1h1b, ushort* pw1b)
{
    const long total = 17956864;
    for (long idx = (long)blockIdx.x * 256 + threadIdx.x; idx < total; idx += (long)gridDim.x * 256) {
        long l = idx;
        if (l < 3145728) { wihb[l] = f2b(w_ih[l]); continue; } l -= 3145728;
        if (l < 3145728) { whhb[l] = f2b(w_hh[l]); continue; } l -= 3145728;
        if (l < 2097152) { w2b[l] = f2b(p_w2[l]); continue; } l -= 2097152;
        if (l < 1048576) { muwb[l] = f2b(mu_w[l]); continue; } l -= 1048576;
        if (l < 1048576) { lvwb[l] = f2b(lv_w[l]); continue; } l -= 1048576;
        if (l < 1048576) {
            int c = (int)(l >> 10), o = (int)(l & 1023);
            muwTb[l] = f2b(mu_w[(size_t)o * 1024 + c]); continue;
        } l -= 1048576;
        if (l < 2097152) {
            int r = (int)(l >> 10), c = (int)(l & 1023);
            w1h1b[l] = f2b(p_w1[(size_t)r * 2064 + 16 + c]); continue;
        } l -= 2097152;
        {
            int r = (int)(l / 2112), c = (int)(l - (long)r * 2112);
            pw1b[l] = (c < 2064) ? f2b(p_w1[(size_t)r * 2064 + c]) : (ushort)0;
        }
    }
}

__global__ void prep_x(const float* x, const float* hxs_g, const float* hxs_p,
                       const float* masks, const float* oh,
                       ushort* ain, ushort* hb0, ushort* hp1b)
{
    const long totA = 8192L * 2112, totH = 131072, totP = 131072;
    for (long idx = (long)blockIdx.x * 256 + threadIdx.x; idx < totA + totH + totP; idx += (long)gridDim.x * 256) {
        if (idx < totA) {
            long j = idx;
            int i = (int)(j / 2112);
            int c = (int)(j - (long)i * 2112);
            float m = masks[i];
            float v;
            if (c < 16) v = oh[(size_t)i * 16 + c] * m;
            else if (c < 1040) v = x[(size_t)i * 1024 + (c - 16)] * (1.f - m);
            else if (c < 2064) {
                int cc = c - 1040;
                float xp = (i >= 128) ? x[(size_t)(i - 128) * 1024 + cc]
                                      : hxs_p[(size_t)i * 2048 + 1024 + cc];
                v = xp * m + x[(size_t)i * 1024 + cc] * (1.f - m);
            } else v = 0.f;
            ain[j] = f2b(v);
            continue;
        }
        long j = idx - totA;
        if (j < totH) {
            int row = (int)(j >> 10), c = (int)(j & 1023);
            hb0[j] = f2b(hxs_g[(size_t)row * 1024 + c] * masks[row]);
            continue;
        }
        j -= totH;
        {
            int row = (int)(j >> 10), c = (int)(j & 1023);
            hp1b[j] = f2b(hxs_p[(size_t)row * 2048 + c]);
        }
    }
}

__global__ void k_cvec(const float* p_w1, const float* mu_b, float* cvec)
{
    int j = blockIdx.x * 4 + (threadIdx.x >> 6);
    int lane = threadIdx.x & 63;
    float s = 0.f;
    for (int o = lane; o < 1024; o += 64) s += p_w1[(size_t)j * 2064 + 16 + o] * mu_b[o];
#pragma unroll
    for (int off = 32; off; off >>= 1) s += __shfl_down(s, off);
    if (lane == 0) cvec[j] = s;
}

__global__ void init_flags(uint* cnt)
{
    int i = blockIdx.x * 256 + threadIdx.x;
    if (i < 20480) cnt[i] = 0u;
}

__global__ void k_tail(float* out, const float* x)
{
    const long total = 131072 + 262144;
    for (long idx = (long)blockIdx.x * 256 + threadIdx.x; idx < total; idx += (long)gridDim.x * 256) {
        if (idx < 131072) {
            out[8388608 + idx] = out[8257536 + idx];        // gru_hxs = h_{63}
        } else {
            long j = idx - 131072;
            int n = (int)(j >> 11), c = (int)(j & 2047);
            out[25296896 + j] = (c < 1024)
                ? out[8519680 + (size_t)(8064 + n) * 1024 + c]       // mu_{63}
                : x[(size_t)(8064 + n) * 1024 + (c - 1024)];         // x_{63}
        }
    }
}

// ---------- launch ----------
extern "C" void kernel_launch(void* const* d_in, const int* in_sizes, int n_in,
                              void* d_out, int out_size, void* d_ws, size_t ws_size,
                              hipStream_t stream)
{
    (void)in_sizes; (void)n_in; (void)out_size; (void)ws_size;
    const float* x      = (const float*)d_in[0];
    const float* hxs_g  = (const float*)d_in[1];
    const float* hxs_p  = (const float*)d_in[2];
    const float* masks  = (const float*)d_in[3];
    const float* oh     = (const float*)d_in[4];
    const float* w_ih   = (const float*)d_in[5];
    const float* w_hh   = (const float*)d_in[6];
    const float* b_ih   = (const float*)d_in[7];
    const float* b_hh   = (const float*)d_in[8];
    const float* p_w1   = (const float*)d_in[9];
    const float* p_b1   = (const float*)d_in[10];
    const float* p_w2   = (const float*)d_in[11];
    const float* p_b2   = (const float*)d_in[12];
    const float* mu_w   = (const float*)d_in[13];
    const float* mu_b   = (const float*)d_in[14];
    const float* lv_w   = (const float*)d_in[15];
    const float* lv_b   = (const float*)d_in[16];
    float* out = (float*)d_out;

    char* w = (char*)d_ws;
    ushort* gi     = (ushort*)(w + 0);           // [8192][3072] bf16 (aliases ain)
    ushort* ain    = (ushort*)(w + 0);           // [8192][2112] bf16, dead after d1pre GEMM
    ushort* d1pre  = (ushort*)(w + 50331648);    // [8192][2048]
    ushort* wihb   = (ushort*)(w + 83886080);    // [3072][1024]
    ushort* whhb   = (ushort*)(w + 90177536);    // [3072][1024]
    ushort* pw1b   = (ushort*)(w + 96468992);    // [2048][2112]
    ushort* w1h1b  = (ushort*)(w + 105119744);   // [2048][1024]
    ushort* w2b    = (ushort*)(w + 109314048);   // [1024][2048]
    ushort* muwb   = (ushort*)(w + 113508352);   // [1024][1024]
    ushort* muwTb  = (ushort*)(w + 115605504);   // [1024][1024]
    ushort* lvwb   = (ushort*)(w + 117702656);   // [1024][1024]
    ushort* Wcb    = (ushort*)(w + 119799808);   // [2048][1024]
    ushort* hp1b   = (ushort*)(w + 123994112);   // [128][1024]
    ushort* hb     = (ushort*)(w + 124256256);   // [64][128][1024] t-indexed, 16 MB
    ushort* d1r    = (ushort*)(w + 141033472);   // [64][128][2048] t-indexed, 32 MB
    ushort* d2r    = (ushort*)(w + 174587904);   // [64][128][1024] t-indexed, 16 MB
    float*  cvec   = (float*) (w + 191365120);   // [2048]
    uint*   cnt    = (uint*)  (w + 191373312);   // 20480 uints (1280 counters x 64B)
    // total ws need: 191455232 bytes

    prep_w<<<dim3(2048), 256, 0, stream>>>(w_ih, w_hh, p_w1, p_w2, mu_w, lv_w,
                                           wihb, whhb, w2b, muwb, lvwb, muwTb, w1h1b, pw1b);
    prep_x<<<dim3(4096), 256, 0, stream>>>(x, hxs_g, hxs_p, masks, oh, ain, hb, hp1b);
    k_cvec<<<dim3(512), 256, 0, stream>>>(p_w1, mu_b, cvec);
    init_flags<<<dim3(80), 256, 0, stream>>>(cnt);

    // d1pre = Ain @ p_w1^T + b1   [8192 x 2048], K=2112   (consumes ain)
    gemm_k<128, 2, false><<<dim3(16, 64), 256, 0, stream>>>(
        ain, 2112, pw1b, 2112, 2112, d1pre, 2048, p_b1);
    // gi = x @ w_ih^T   [8192 x 3072], K=1024  (overwrites ain region)
    gemm_k<128, 1, true><<<dim3(24, 64), 256, 0, stream>>>(
        x, 1024, wihb, 1024, 1024, gi, 3072, nullptr);
    // Wc = W1h1 @ mu_w   [2048 x 1024], K=1024
    gemm_k<128, 1, false><<<dim3(8, 16), 256, 0, stream>>>(
        w1h1b, 1024, muwTb, 1024, 1024, Wcb, 1024, nullptr);

    // all 64 recurrent steps in one persistent kernel (64 GRU WGs + 128 P WGs)
    persist_k<<<dim3(192), 256, 0, stream>>>(
        whhb, Wcb, w1h1b, w2b, gi, d1pre, hp1b, hb, d1r, d2r,
        masks, b_ih, b_hh, cvec, p_b2, hxs_g, out, cnt);

    // p_mu / p_lv from stored d2r
    gemm_k<128, 0, false><<<dim3(8, 64), 256, 0, stream>>>(
        d2r, 1024, muwb, 1024, 1024, out + 8519680, 1024, mu_b);
    gemm_k<128, 0, false><<<dim3(8, 64), 256, 0, stream>>>(
        d2r, 1024, lvwb, 1024, 1024, out + 16908288, 1024, lv_b);

    k_tail<<<dim3(1536), 256, 0, stream>>>(out, x);
}

// Round 9
// 1409.580 us; speedup vs baseline: 1.2730x; 1.2730x over previous
//
#include <hip/hip_runtime.h>

typedef unsigned int uint;
typedef unsigned short ushort;
typedef __bf16 bf16x8_t __attribute__((ext_vector_type(8)));
typedef float f32x4_t __attribute__((ext_vector_type(4)));
typedef uint u32x4_t __attribute__((ext_vector_type(4)));

// ---------- helpers ----------
__device__ __forceinline__ ushort f2b(float f) {
    uint u = __builtin_bit_cast(uint, f);
    u += 0x7fffu + ((u >> 16) & 1u);   // RNE
    return (ushort)(u >> 16);
}
__device__ __forceinline__ float b2f(ushort h) {
    return __builtin_bit_cast(float, (uint)h << 16);
}
__device__ __forceinline__ float sigm(float v) { return 1.f / (1.f + __expf(-v)); }
__device__ __forceinline__ float tanh_(float v) {
    v = fmaxf(-15.f, fminf(15.f, v));
    float e = __expf(2.f * v);
    return (e - 1.f) / (e + 1.f);
}

// ---------- coherent primitives (flags + publishes only) ----------
__device__ __forceinline__ uint ld_cg_u32(const uint* p) {
    uint r;
    asm volatile("global_load_dword %0, %1, off sc0 sc1\n\ts_waitcnt vmcnt(0)"
                 : "=v"(r) : "v"(p) : "memory");
    return r;
}
__device__ __forceinline__ void st_cg_u32(uint* p, uint v) {
    asm volatile("global_store_dword %0, %1, off sc0 sc1" :: "v"(p), "v"(v) : "memory");
}
__device__ __forceinline__ void st_cg_u16(ushort* p, uint v) {
    asm volatile("global_store_short %0, %1, off sc0 sc1" :: "v"(p), "v"(v) : "memory");
}
__device__ __forceinline__ void st_cg_x4(ushort* p, u32x4_t v) {
    asm volatile("global_store_dwordx4 %0, %1, off sc0 sc1" :: "v"(p), "v"(v) : "memory");
}
// 8 CACHED 16B loads issued without waiting (t-indexed buffers are first-touch safe).
__device__ __forceinline__ void ld8_nc(uint4 u[8],
    const void* p0, const void* p1, const void* p2, const void* p3,
    const void* p4, const void* p5, const void* p6, const void* p7)
{
    asm volatile(
        "global_load_dwordx4 %0, %8, off\n\t"
        "global_load_dwordx4 %1, %9, off\n\t"
        "global_load_dwordx4 %2, %10, off\n\t"
        "global_load_dwordx4 %3, %11, off\n\t"
        "global_load_dwordx4 %4, %12, off\n\t"
        "global_load_dwordx4 %5, %13, off\n\t"
        "global_load_dwordx4 %6, %14, off\n\t"
        "global_load_dwordx4 %7, %15, off"
        : "=&v"(u[0]), "=&v"(u[1]), "=&v"(u[2]), "=&v"(u[3]),
          "=&v"(u[4]), "=&v"(u[5]), "=&v"(u[6]), "=&v"(u[7])
        : "v"(p0), "v"(p1), "v"(p2), "v"(p3), "v"(p4), "v"(p5), "v"(p6), "v"(p7)
        : "memory");
}
__device__ __forceinline__ void vm0() {
    asm volatile("s_waitcnt vmcnt(0)" ::: "memory");
    __builtin_amdgcn_sched_barrier(0);   // rule #18
}
__device__ __forceinline__ bf16x8_t u2b(uint4 u) { return __builtin_bit_cast(bf16x8_t, u); }

#define SMEM_BYTES 36864
union U8 { ushort h[8]; uint4 v; };

// ---------- generic bf16 GEMM body: C = A @ B^T (+epilogue) ----------
// EPI: 0 f32+bias; 1 bf16; 2 bf16+bias; 3 gi-blocked bf16; 4 d1pre-blocked bf16+bias
template<int BN, int EPI, bool AF32>
__device__ __forceinline__ void gemm_body(
    int bx, int by, const void* Av, int lda,
    const ushort* Bp, int ldb, int K,
    void* Ov, int ldo, const float* bias, char* smem)
{
    constexpr int LDW = 72;
    ushort* As = (ushort*)smem;
    ushort* Bs = (ushort*)(smem + 128 * LDW * 2);
    const int tid = threadIdx.x, lane = tid & 63, wid = tid >> 6;
    constexpr int WC = (BN == 128) ? 2 : 1;
    constexpr int WR = 4 / WC;
    constexpr int WROWS = 128 / WR;
    constexpr int WCOLS = BN / WC;
    constexpr int MI = WROWS / 16, NI = WCOLS / 16;
    const int wr = (WC == 2) ? (wid >> 1) : wid;
    const int wc = (WC == 2) ? (wid & 1) : 0;
    const int row0 = by * 128, col0 = bx * BN;

    f32x4_t acc[MI][NI];
#pragma unroll
    for (int i = 0; i < MI; i++)
#pragma unroll
        for (int j = 0; j < NI; j++) acc[i][j] = (f32x4_t){0.f, 0.f, 0.f, 0.f};

    for (int k0 = 0; k0 < K; k0 += 64) {
        __syncthreads();
#pragma unroll
        for (int cc = 0; cc < 4; cc++) {
            int chunk = tid + cc * 256;
            int r = chunk >> 3, c8 = chunk & 7;
            uint4 val;
            if constexpr (AF32) {
                const float* Af = (const float*)Av + (size_t)(row0 + r) * lda + k0 + c8 * 8;
                float4 v0 = ((const float4*)Af)[0];
                float4 v1 = ((const float4*)Af)[1];
                U8 u;
                u.h[0] = f2b(v0.x); u.h[1] = f2b(v0.y); u.h[2] = f2b(v0.z); u.h[3] = f2b(v0.w);
                u.h[4] = f2b(v1.x); u.h[5] = f2b(v1.y); u.h[6] = f2b(v1.z); u.h[7] = f2b(v1.w);
                val = u.v;
            } else {
                val = *(const uint4*)((const ushort*)Av + (size_t)(row0 + r) * lda + k0 + c8 * 8);
            }
            *(uint4*)&As[r * LDW + c8 * 8] = val;
        }
#pragma unroll
        for (int cc = 0; cc < BN / 32; cc++) {
            int chunk = tid + cc * 256;
            int r = chunk >> 3, c8 = chunk & 7;
            uint4 val = *(const uint4*)(Bp + (size_t)(col0 + r) * ldb + k0 + c8 * 8);
            *(uint4*)&Bs[r * LDW + c8 * 8] = val;
        }
        __syncthreads();
#pragma unroll
        for (int kk = 0; kk < 64; kk += 32) {
            int ko = kk + ((lane >> 4) << 3);
            bf16x8_t af[MI], bf[NI];
#pragma unroll
            for (int mi = 0; mi < MI; mi++)
                af[mi] = *(const bf16x8_t*)&As[(wr * WROWS + mi * 16 + (lane & 15)) * LDW + ko];
#pragma unroll
            for (int ni = 0; ni < NI; ni++)
                bf[ni] = *(const bf16x8_t*)&Bs[(wc * WCOLS + ni * 16 + (lane & 15)) * LDW + ko];
#pragma unroll
            for (int mi = 0; mi < MI; mi++)
#pragma unroll
                for (int ni = 0; ni < NI; ni++)
                    acc[mi][ni] = __builtin_amdgcn_mfma_f32_16x16x32_bf16(af[mi], bf[ni], acc[mi][ni], 0, 0, 0);
        }
    }
#pragma unroll
    for (int mi = 0; mi < MI; mi++) {
#pragma unroll
        for (int ni = 0; ni < NI; ni++) {
            int gcol = col0 + wc * WCOLS + ni * 16 + (lane & 15);
#pragma unroll
            for (int i = 0; i < 4; i++) {
                int grow = row0 + wr * WROWS + mi * 16 + ((lane >> 4) << 2) + i;
                float v = acc[mi][ni][i];
                if constexpr (EPI == 0) {
                    ((float*)Ov)[(size_t)grow * ldo + gcol] = v + bias[gcol];
                } else if constexpr (EPI == 1) {
                    ((ushort*)Ov)[(size_t)grow * ldo + gcol] = f2b(v);
                } else if constexpr (EPI == 2) {
                    ((ushort*)Ov)[(size_t)grow * ldo + gcol] = f2b(v + bias[gcol]);
                } else if constexpr (EPI == 3) {
                    // gi blocked: [(t*3+g)*64+cb][128][16]
                    int t = grow >> 7, row = grow & 127;
                    int g = gcol >> 10, cb = (gcol & 1023) >> 4, c16 = gcol & 15;
                    ((ushort*)Ov)[(((size_t)t * 3 + g) * 64 + cb) * 2048 + row * 16 + c16] = f2b(v);
                } else {
                    // d1pre blocked: [t*64+colg][128][32]
                    int t = grow >> 7, row = grow & 127;
                    int cg = gcol >> 5, c32 = gcol & 31;
                    ((ushort*)Ov)[((size_t)t * 64 + cg) * 4096 + row * 32 + c32] = f2b(v + bias[gcol]);
                }
            }
        }
    }
}

template<int BN, int EPI, bool AF32>
__global__ __launch_bounds__(256) void gemm_k(
    const void* A, int lda, const ushort* B, int ldb, int K,
    void* O, int ldo, const float* bias)
{
    __shared__ char smem[SMEM_BYTES];
    gemm_body<BN, EPI, AF32>(blockIdx.x, blockIdx.y, A, lda, B, ldb, K, O, ldo, bias, smem);
}

// ---------- persistent-kernel sync (R6-proven flag protocol) ----------
#define NFLAG_G 0        // [0,4096):      GRU   t*64 + cb
#define NFLAG_A 4096     // [4096,12288):  P phA t*128 + p
#define NFLAG_B 12288    // [12288,20480): P phB t*128 + p
#define NFLAGS  20480

__device__ __forceinline__ void wg_wait(uint* f, int n, int tid) {
    if (tid < n) {
        while (ld_cg_u32(f + tid) == 0u) __builtin_amdgcn_s_sleep(1);
    }
    __syncthreads();
}
__device__ __forceinline__ void wg_arrive(uint* slot, int tid) {
    __syncthreads();
    if (tid == 0) st_cg_u32(slot, 1u);
}

// ---------- GRU role: 64 WGs, each owns 16 h-cols x 128 rows ----------
// hb t-indexed: hb + t*131072.
__device__ void role_gru(int cb, const ushort* __restrict__ whhb, ushort* hb,
                         const ushort* __restrict__ gi, const float* masks,
                         const float* b_ih, const float* b_hh, const float* hxs_g,
                         float* out, uint* flags, char* lds)
{
    const int tid = threadIdx.x, lane = tid & 63, w = tid >> 6;
    const int colL = cb * 16 + (lane & 15);
    const int kw = w * 256;
    const int kl = (lane >> 4) << 3;

    bf16x8_t bw[3][8];
#pragma unroll
    for (int g = 0; g < 3; g++)
#pragma unroll
        for (int ks = 0; ks < 8; ks++)
            bw[g][ks] = *(const bf16x8_t*)(whhb + (size_t)(g * 1024 + colL) * 1024 + kw + ks * 32 + kl);

    const float bihr = b_ih[colL], bihz = b_ih[1024 + colL], bihn = b_ih[2048 + colL];
    const float bhhr = b_hh[colL], bhhz = b_hh[1024 + colL], bhhn = b_hh[2048 + colL];

    f32x4_t hown[2];
#pragma unroll
    for (int j = 0; j < 2; j++)
#pragma unroll
        for (int i = 0; i < 4; i++)
            hown[j][i] = hxs_g[(size_t)((2 * w + j) * 16 + ((lane >> 4) << 2) + i) * 1024 + colL];

    for (int t = 0; t < 64; t++) {
        // prefetch epilogue operands from BLOCKED gi (contiguous lines) before the wait
        float mc[2][4], mn[2][4], g0p[2][4], g1p[2][4], g2p[2][4];
        const size_t gb = ((size_t)t * 3 * 64 + cb) * 2048;
#pragma unroll
        for (int j = 0; j < 2; j++) {
            const int rt = 2 * w + j;
#pragma unroll
            for (int i = 0; i < 4; i++) {
                const int row = rt * 16 + ((lane >> 4) << 2) + i;
                mc[j][i] = masks[t * 128 + row];
                mn[j][i] = (t < 63) ? masks[(t + 1) * 128 + row] : 0.f;
                g0p[j][i] = b2f(gi[gb + row * 16 + (lane & 15)]);
                g1p[j][i] = b2f(gi[gb + 131072 + row * 16 + (lane & 15)]);
                g2p[j][i] = b2f(gi[gb + 262144 + row * 16 + (lane & 15)]);
            }
        }
        if (t) wg_wait(flags + NFLAG_G + (t - 1) * 64, 64, tid);
        const ushort* base = hb + (size_t)t * 131072 + (size_t)(lane & 15) * 1024 + kw + kl;
        f32x4_t acc[3][8];
#pragma unroll
        for (int g = 0; g < 3; g++)
#pragma unroll
            for (int rt = 0; rt < 8; rt++) acc[g][rt] = (f32x4_t){0.f, 0.f, 0.f, 0.f};
#pragma unroll
        for (int half = 0; half < 2; half++) {
            const ushort* b = base + half * 128;
            uint4 u0[8], u1[8], u2[8], u3[8];
            ld8_nc(u0, b, b + 16384, b + 32768, b + 49152, b + 65536, b + 81920, b + 98304, b + 114688);
            ld8_nc(u1, b + 32, b + 16384 + 32, b + 32768 + 32, b + 49152 + 32, b + 65536 + 32, b + 81920 + 32, b + 98304 + 32, b + 114688 + 32);
            ld8_nc(u2, b + 64, b + 16384 + 64, b + 32768 + 64, b + 49152 + 64, b + 65536 + 64, b + 81920 + 64, b + 98304 + 64, b + 114688 + 64);
            ld8_nc(u3, b + 96, b + 16384 + 96, b + 32768 + 96, b + 49152 + 96, b + 65536 + 96, b + 81920 + 96, b + 98304 + 96, b + 114688 + 96);
            vm0();
#pragma unroll
            for (int g = 0; g < 3; g++)
#pragma unroll
                for (int rt = 0; rt < 8; rt++) {
                    acc[g][rt] = __builtin_amdgcn_mfma_f32_16x16x32_bf16(u2b(u0[rt]), bw[g][half * 4 + 0], acc[g][rt], 0, 0, 0);
                    acc[g][rt] = __builtin_amdgcn_mfma_f32_16x16x32_bf16(u2b(u1[rt]), bw[g][half * 4 + 1], acc[g][rt], 0, 0, 0);
                    acc[g][rt] = __builtin_amdgcn_mfma_f32_16x16x32_bf16(u2b(u2[rt]), bw[g][half * 4 + 2], acc[g][rt], 0, 0, 0);
                    acc[g][rt] = __builtin_amdgcn_mfma_f32_16x16x32_bf16(u2b(u3[rt]), bw[g][half * 4 + 3], acc[g][rt], 0, 0, 0);
                }
        }
#pragma unroll
        for (int g = 0; g < 3; g++)
#pragma unroll
            for (int rt = 0; rt < 8; rt++)
                *(f32x4_t*)(lds + ((size_t)(w * 24 + g * 8 + rt) * 64 + lane) * 16) = acc[g][rt];
        __syncthreads();
#pragma unroll
        for (int j = 0; j < 2; j++) {
            const int rt = 2 * w + j;
            f32x4_t sg[3];
#pragma unroll
            for (int g = 0; g < 3; g++) {
                sg[g] = (f32x4_t){0.f, 0.f, 0.f, 0.f};
#pragma unroll
                for (int ww = 0; ww < 4; ww++)
                    sg[g] += *(const f32x4_t*)(lds + ((size_t)(ww * 24 + g * 8 + rt) * 64 + lane) * 16);
            }
#pragma unroll
            for (int i = 0; i < 4; i++) {
                const int row = rt * 16 + ((lane >> 4) << 2) + i;
                const float h0 = hown[j][i] * mc[j][i];
                const float rv = sigm(g0p[j][i] + bihr + bhhr + sg[0][i]);
                const float zv = sigm(g1p[j][i] + bihz + bhhz + sg[1][i]);
                const float nv = tanh_(g2p[j][i] + bihn + rv * (sg[2][i] + bhhn));
                const float hnew = (1.f - zv) * nv + zv * h0;
                out[(size_t)(t * 128 + row) * 1024 + colL] = hnew;
                hown[j][i] = hnew;
                if (t < 63)
                    st_cg_u16(hb + (size_t)(t + 1) * 131072 + (size_t)row * 1024 + colL,
                              (uint)f2b(hnew * mn[j][i]));
            }
        }
        wg_arrive(flags + NFLAG_G + t * 64 + cb, tid);
    }
}

// ---------- P role: 128 WGs, phase A (d1) then phase B (d2) per step ----------
// d1r t-indexed (stride 262144), d2r t-indexed (stride 131072), d1pre blocked.
__device__ void role_p(int p, const ushort* __restrict__ Wcb, const ushort* __restrict__ w1h1b,
                       const ushort* __restrict__ hp1b, const ushort* __restrict__ w2b,
                       const ushort* __restrict__ d1pre, const float* masks, const float* cvec,
                       const float* p_b2, ushort* d1r, ushort* d2r, uint* flags, char* lds)
{
    const int tid = threadIdx.x, lane = tid & 63, w = tid >> 6;
    const int rowg = p >> 6, colg = p & 63;
    const int rA0 = rowg * 64, cA0 = colg * 32;
    const int rB0 = rowg * 64, cB0 = colg * 16;
    const int kwA = w * 256, kwB = w * 512, kl = (lane >> 4) << 3;
    ushort* stg = (ushort*)(lds + 32768) + w * 512;   // per-wave 1KB staging

    bf16x8_t wcF[2][8];
#pragma unroll
    for (int ct = 0; ct < 2; ct++)
#pragma unroll
        for (int ks = 0; ks < 8; ks++)
            wcF[ct][ks] = *(const bf16x8_t*)(Wcb + (size_t)(cA0 + ct * 16 + (lane & 15)) * 1024 + kwA + ks * 32 + kl);
    bf16x8_t w2F[16];
#pragma unroll
    for (int ks = 0; ks < 16; ks++)
        w2F[ks] = *(const bf16x8_t*)(w2b + (size_t)(cB0 + (lane & 15)) * 2048 + kwB + ks * 32 + kl);
    const float cv0 = cvec[cA0 + (lane & 15)], cv1 = cvec[cA0 + 16 + (lane & 15)];
    const float pb = p_b2[cB0 + (lane & 15)];

    for (int t = 0; t < 64; t++) {
        // prefetch from BLOCKED d1pre (contiguous lines) before the wait
        float mA[4], preA[2][4];
        const size_t pbase = ((size_t)t * 64 + colg) * 4096;
#pragma unroll
        for (int i = 0; i < 4; i++) {
            const int row = rA0 + w * 16 + ((lane >> 4) << 2) + i;
            mA[i] = masks[t * 128 + row];
            preA[0][i] = b2f(d1pre[pbase + (row & 127) * 32 + (lane & 15)]);
            preA[1][i] = b2f(d1pre[pbase + (row & 127) * 32 + 16 + (lane & 15)]);
        }
        if (t) wg_wait(flags + NFLAG_B + (t - 1) * 128 + rowg * 64, 64, tid);
        // ---- phase A ----
        f32x4_t accA[2][4];
#pragma unroll
        for (int ct = 0; ct < 2; ct++)
#pragma unroll
            for (int rt = 0; rt < 4; rt++) accA[ct][rt] = (f32x4_t){0.f, 0.f, 0.f, 0.f};
        if (t == 0) {
#pragma unroll
            for (int ks = 0; ks < 8; ks++) {
                bf16x8_t af[4], b0[2];
#pragma unroll
                for (int ct = 0; ct < 2; ct++)
                    b0[ct] = *(const bf16x8_t*)(w1h1b + (size_t)(cA0 + ct * 16 + (lane & 15)) * 1024 + kwA + ks * 32 + kl);
#pragma unroll
                for (int rt = 0; rt < 4; rt++)
                    af[rt] = *(const bf16x8_t*)(hp1b + (size_t)(rA0 + rt * 16 + (lane & 15)) * 1024 + kwA + ks * 32 + kl);
#pragma unroll
                for (int ct = 0; ct < 2; ct++)
#pragma unroll
                    for (int rt = 0; rt < 4; rt++)
                        accA[ct][rt] = __builtin_amdgcn_mfma_f32_16x16x32_bf16(af[rt], b0[ct], accA[ct][rt], 0, 0, 0);
            }
        } else {
            const ushort* Ab = d2r + (size_t)(t - 1) * 131072 + (size_t)(rA0 + (lane & 15)) * 1024 + kwA + kl;
            uint4 u0[8], u1[8], u2[8], u3[8];
            ld8_nc(u0, Ab,       Ab + 16384,       Ab + 32768,       Ab + 49152,       Ab + 32,  Ab + 16384 + 32,  Ab + 32768 + 32,  Ab + 49152 + 32);
            ld8_nc(u1, Ab + 64,  Ab + 16384 + 64,  Ab + 32768 + 64,  Ab + 49152 + 64,  Ab + 96,  Ab + 16384 + 96,  Ab + 32768 + 96,  Ab + 49152 + 96);
            ld8_nc(u2, Ab + 128, Ab + 16384 + 128, Ab + 32768 + 128, Ab + 49152 + 128, Ab + 160, Ab + 16384 + 160, Ab + 32768 + 160, Ab + 49152 + 160);
            ld8_nc(u3, Ab + 192, Ab + 16384 + 192, Ab + 32768 + 192, Ab + 49152 + 192, Ab + 224, Ab + 16384 + 224, Ab + 32768 + 224, Ab + 49152 + 224);
            vm0();
#pragma unroll
            for (int ct = 0; ct < 2; ct++)
#pragma unroll
                for (int rt = 0; rt < 4; rt++) {
                    accA[ct][rt] = __builtin_amdgcn_mfma_f32_16x16x32_bf16(u2b(u0[rt]), wcF[ct][0], accA[ct][rt], 0, 0, 0);
                    accA[ct][rt] = __builtin_amdgcn_mfma_f32_16x16x32_bf16(u2b(u0[4 + rt]), wcF[ct][1], accA[ct][rt], 0, 0, 0);
                    accA[ct][rt] = __builtin_amdgcn_mfma_f32_16x16x32_bf16(u2b(u1[rt]), wcF[ct][2], accA[ct][rt], 0, 0, 0);
                    accA[ct][rt] = __builtin_amdgcn_mfma_f32_16x16x32_bf16(u2b(u1[4 + rt]), wcF[ct][3], accA[ct][rt], 0, 0, 0);
                    accA[ct][rt] = __builtin_amdgcn_mfma_f32_16x16x32_bf16(u2b(u2[rt]), wcF[ct][4], accA[ct][rt], 0, 0, 0);
                    accA[ct][rt] = __builtin_amdgcn_mfma_f32_16x16x32_bf16(u2b(u2[4 + rt]), wcF[ct][5], accA[ct][rt], 0, 0, 0);
                    accA[ct][rt] = __builtin_amdgcn_mfma_f32_16x16x32_bf16(u2b(u3[rt]), wcF[ct][6], accA[ct][rt], 0, 0, 0);
                    accA[ct][rt] = __builtin_amdgcn_mfma_f32_16x16x32_bf16(u2b(u3[4 + rt]), wcF[ct][7], accA[ct][rt], 0, 0, 0);
                }
        }
        __syncthreads();
#pragma unroll
        for (int ct = 0; ct < 2; ct++)
#pragma unroll
            for (int rt = 0; rt < 4; rt++)
                *(f32x4_t*)(lds + ((size_t)(w * 8 + ct * 4 + rt) * 64 + lane) * 16) = accA[ct][rt];
        __syncthreads();
#pragma unroll
        for (int ct = 0; ct < 2; ct++) {
            f32x4_t s = (f32x4_t){0.f, 0.f, 0.f, 0.f};
#pragma unroll
            for (int ww = 0; ww < 4; ww++)
                s += *(const f32x4_t*)(lds + ((size_t)(ww * 8 + ct * 4 + w) * 64 + lane) * 16);
            const float cvt = (t == 0) ? 0.f : (ct ? cv1 : cv0);
#pragma unroll
            for (int i = 0; i < 4; i++) {
                float f = preA[ct][i] + mA[i] * (s[i] + cvt);
                stg[(((lane >> 4) << 2) + i) * 32 + ct * 16 + (lane & 15)] = f2b(f > 0.f ? f : 0.f);
            }
        }
        __syncthreads();
        {   // coalesced publish: 1 dwordx4/lane (16 rows x 32 cols per wave)
            const int rl = lane >> 2, c8 = (lane & 3) * 8;
            u32x4_t v = *(const u32x4_t*)&stg[rl * 32 + c8];
            st_cg_x4(d1r + (size_t)t * 262144 + (size_t)(rA0 + w * 16 + rl) * 2048 + cA0 + c8, v);
        }
        wg_arrive(flags + NFLAG_A + t * 128 + p, tid);
        wg_wait(flags + NFLAG_A + t * 128 + rowg * 64, 64, tid);
        // ---- phase B ----
        f32x4_t accB[4];
#pragma unroll
        for (int rt = 0; rt < 4; rt++) accB[rt] = (f32x4_t){0.f, 0.f, 0.f, 0.f};
        const ushort* Bb = d1r + (size_t)t * 262144 + (size_t)(rB0 + (lane & 15)) * 2048 + kwB + kl;
#pragma unroll
        for (int half = 0; half < 2; half++) {
            const ushort* b = Bb + half * 256;
            uint4 u0[8], u1[8], u2[8], u3[8];
            ld8_nc(u0, b,       b + 32768,       b + 65536,       b + 98304,       b + 32,  b + 32768 + 32,  b + 65536 + 32,  b + 98304 + 32);
            ld8_nc(u1, b + 64,  b + 32768 + 64,  b + 65536 + 64,  b + 98304 + 64,  b + 96,  b + 32768 + 96,  b + 65536 + 96,  b + 98304 + 96);
            ld8_nc(u2, b + 128, b + 32768 + 128, b + 65536 + 128, b + 98304 + 128, b + 160, b + 32768 + 160, b + 65536 + 160, b + 98304 + 160);
            ld8_nc(u3, b + 192, b + 32768 + 192, b + 65536 + 192, b + 98304 + 192, b + 224, b + 32768 + 224, b + 65536 + 224, b + 98304 + 224);
            vm0();
#pragma unroll
            for (int rt = 0; rt < 4; rt++) {
                accB[rt] = __builtin_amdgcn_mfma_f32_16x16x32_bf16(u2b(u0[rt]), w2F[half * 8 + 0], accB[rt], 0, 0, 0);
                accB[rt] = __builtin_amdgcn_mfma_f32_16x16x32_bf16(u2b(u0[4 + rt]), w2F[half * 8 + 1], accB[rt], 0, 0, 0);
                accB[rt] = __builtin_amdgcn_mfma_f32_16x16x32_bf16(u2b(u1[rt]), w2F[half * 8 + 2], accB[rt], 0, 0, 0);
                accB[rt] = __builtin_amdgcn_mfma_f32_16x16x32_bf16(u2b(u1[4 + rt]), w2F[half * 8 + 3], accB[rt], 0, 0, 0);
                accB[rt] = __builtin_amdgcn_mfma_f32_16x16x32_bf16(u2b(u2[rt]), w2F[half * 8 + 4], accB[rt], 0, 0, 0);
                accB[rt] = __builtin_amdgcn_mfma_f32_16x16x32_bf16(u2b(u2[4 + rt]), w2F[half * 8 + 5], accB[rt], 0, 0, 0);
                accB[rt] = __builtin_amdgcn_mfma_f32_16x16x32_bf16(u2b(u3[rt]), w2F[half * 8 + 6], accB[rt], 0, 0, 0);
                accB[rt] = __builtin_amdgcn_mfma_f32_16x16x32_bf16(u2b(u3[4 + rt]), w2F[half * 8 + 7], accB[rt], 0, 0, 0);
            }
        }
        __syncthreads();
#pragma unroll
        for (int rt = 0; rt < 4; rt++)
            *(f32x4_t*)(lds + ((size_t)(w * 4 + rt) * 64 + lane) * 16) = accB[rt];
        __syncthreads();
        {
            f32x4_t s = (f32x4_t){0.f, 0.f, 0.f, 0.f};
#pragma unroll
            for (int ww = 0; ww < 4; ww++)
                s += *(const f32x4_t*)(lds + ((size_t)(ww * 4 + w) * 64 + lane) * 16);
#pragma unroll
            for (int i = 0; i < 4; i++) {
                float f = s[i] + pb;
                stg[(((lane >> 4) << 2) + i) * 16 + (lane & 15)] = f2b(f > 0.f ? f : 0.f);
            }
        }
        __syncthreads();
        {   // coalesced publish: 32 lanes x dwordx4 (16 rows x 16 cols per wave)
            if (lane < 32) {
                const int rl = lane >> 1, c8 = (lane & 1) * 8;
                u32x4_t v = *(const u32x4_t*)&stg[rl * 16 + c8];
                st_cg_x4(d2r + (size_t)t * 131072 + (size_t)(rB0 + w * 16 + rl) * 1024 + cB0 + c8, v);
            }
        }
        wg_arrive(flags + NFLAG_B + t * 128 + p, tid);
    }
}

__global__ __launch_bounds__(256, 1) void persist_k(
    const ushort* whhb, const ushort* Wcb, const ushort* w1h1b, const ushort* w2b,
    const ushort* gi, const ushort* d1pre, const ushort* hp1b,
    ushort* hb, ushort* d1r, ushort* d2r,
    const float* masks, const float* b_ih, const float* b_hh,
    const float* cvec, const float* p_b2, const float* hxs_g,
    float* out, uint* flags)
{
    __shared__ __align__(16) char lds[98304];
    const int wg = blockIdx.x;
    if (wg < 64) role_gru(wg, whhb, hb, gi, masks, b_ih, b_hh, hxs_g, out, flags, lds);
    else         role_p(wg - 64, Wcb, w1h1b, hp1b, w2b, d1pre, masks, cvec, p_b2, d1r, d2r, flags, lds);
}

// ---------- prep kernels ----------
__global__ void prep_w(const float* w_ih, const float* w_hh, const float* p_w1,
                       const float* p_w2, const float* mu_w, const float* lv_w,
                       ushort* wihb, ushort* whhb, ushort* w2b, ushort* muwb,
                       ushort* lvwb, ushort* muwTb, ushort* w1h1b, ushort* pw1b)
{
    const long total = 17956864;
    for (long idx = (long)blockIdx.x * 256 + threadIdx.x; idx < total; idx += (long)gridDim.x * 256) {
        long l = idx;
        if (l < 3145728) { wihb[l] = f2b(w_ih[l]); continue; } l -= 3145728;
        if (l < 3145728) { whhb[l] = f2b(w_hh[l]); continue; } l -= 3145728;
        if (l < 2097152) { w2b[l] = f2b(p_w2[l]); continue; } l -= 2097152;
        if (l < 1048576) { muwb[l] = f2b(mu_w[l]); continue; } l -= 1048576;
        if (l < 1048576) { lvwb[l] = f2b(lv_w[l]); continue; } l -= 1048576;
        if (l < 1048576) {
            int c = (int)(l >> 10), o = (int)(l & 1023);
            muwTb[l] = f2b(mu_w[(size_t)o * 1024 + c]); continue;
        } l -= 1048576;
        if (l < 2097152) {
            int r = (int)(l >> 10), c = (int)(l & 1023);
            w1h1b[l] = f2b(p_w1[(size_t)r * 2064 + 16 + c]); continue;
        } l -= 2097152;
        {
            int r = (int)(l / 2112), c = (int)(l - (long)r * 2112);
            pw1b[l] = (c < 2064) ? f2b(p_w1[(size_t)r * 2064 + c]) : (ushort)0;
        }
    }
}

__global__ void prep_x(const float* x, const float* hxs_g, const float* hxs_p,
                       const float* masks, const float* oh,
                       ushort* ain, ushort* hb0, ushort* hp1b)
{
    const long totA = 8192L * 2112, totH = 131072, totP = 131072;
    for (long idx = (long)blockIdx.x * 256 + threadIdx.x; idx < totA + totH + totP; idx += (long)gridDim.x * 256) {
        if (idx < totA) {
            long j = idx;
            int i = (int)(j / 2112);
            int c = (int)(j - (long)i * 2112);
            float m = masks[i];
            float v;
            if (c < 16) v = oh[(size_t)i * 16 + c] * m;
            else if (c < 1040) v = x[(size_t)i * 1024 + (c - 16)] * (1.f - m);
            else if (c < 2064) {
                int cc = c - 1040;
                float xp = (i >= 128) ? x[(size_t)(i - 128) * 1024 + cc]
                                      : hxs_p[(size_t)i * 2048 + 1024 + cc];
                v = xp * m + x[(size_t)i * 1024 + cc] * (1.f - m);
            } else v = 0.f;
            ain[j] = f2b(v);
            continue;
        }
        long j = idx - totA;
        if (j < totH) {
            int row = (int)(j >> 10), c = (int)(j & 1023);
            hb0[j] = f2b(hxs_g[(size_t)row * 1024 + c] * masks[row]);
            continue;
        }
        j -= totH;
        {
            int row = (int)(j >> 10), c = (int)(j & 1023);
            hp1b[j] = f2b(hxs_p[(size_t)row * 2048 + c]);
        }
    }
}

__global__ void k_cvec(const float* p_w1, const float* mu_b, float* cvec)
{
    int j = blockIdx.x * 4 + (threadIdx.x >> 6);
    int lane = threadIdx.x & 63;
    float s = 0.f;
    for (int o = lane; o < 1024; o += 64) s += p_w1[(size_t)j * 2064 + 16 + o] * mu_b[o];
#pragma unroll
    for (int off = 32; off; off >>= 1) s += __shfl_down(s, off);
    if (lane == 0) cvec[j] = s;
}

__global__ void init_flags(uint* flags)
{
    int i = blockIdx.x * 256 + threadIdx.x;
    if (i < NFLAGS) flags[i] = 0u;
}

__global__ void k_tail(float* out, const float* x)
{
    const long total = 131072 + 262144;
    for (long idx = (long)blockIdx.x * 256 + threadIdx.x; idx < total; idx += (long)gridDim.x * 256) {
        if (idx < 131072) {
            out[8388608 + idx] = out[8257536 + idx];        // gru_hxs = h_{63}
        } else {
            long j = idx - 131072;
            int n = (int)(j >> 11), c = (int)(j & 2047);
            out[25296896 + j] = (c < 1024)
                ? out[8519680 + (size_t)(8064 + n) * 1024 + c]       // mu_{63}
                : x[(size_t)(8064 + n) * 1024 + (c - 1024)];         // x_{63}
        }
    }
}

// ---------- launch ----------
extern "C" void kernel_launch(void* const* d_in, const int* in_sizes, int n_in,
                              void* d_out, int out_size, void* d_ws, size_t ws_size,
                              hipStream_t stream)
{
    (void)in_sizes; (void)n_in; (void)out_size; (void)ws_size;
    const float* x      = (const float*)d_in[0];
    const float* hxs_g  = (const float*)d_in[1];
    const float* hxs_p  = (const float*)d_in[2];
    const float* masks  = (const float*)d_in[3];
    const float* oh     = (const float*)d_in[4];
    const float* w_ih   = (const float*)d_in[5];
    const float* w_hh   = (const float*)d_in[6];
    const float* b_ih   = (const float*)d_in[7];
    const float* b_hh   = (const float*)d_in[8];
    const float* p_w1   = (const float*)d_in[9];
    const float* p_b1   = (const float*)d_in[10];
    const float* p_w2   = (const float*)d_in[11];
    const float* p_b2   = (const float*)d_in[12];
    const float* mu_w   = (const float*)d_in[13];
    const float* mu_b   = (const float*)d_in[14];
    const float* lv_w   = (const float*)d_in[15];
    const float* lv_b   = (const float*)d_in[16];
    float* out = (float*)d_out;

    char* w = (char*)d_ws;
    ushort* gi     = (ushort*)(w + 0);           // blocked [t*3+g][64][128][16] (aliases ain)
    ushort* ain    = (ushort*)(w + 0);           // [8192][2112], dead after d1pre GEMM
    ushort* d1pre  = (ushort*)(w + 50331648);    // blocked [t*64+cg][128][32]
    ushort* wihb   = (ushort*)(w + 83886080);
    ushort* whhb   = (ushort*)(w + 90177536);
    ushort* pw1b   = (ushort*)(w + 96468992);
    ushort* w1h1b  = (ushort*)(w + 105119744);
    ushort* w2b    = (ushort*)(w + 109314048);
    ushort* muwb   = (ushort*)(w + 113508352);
    ushort* muwTb  = (ushort*)(w + 115605504);
    ushort* lvwb   = (ushort*)(w + 117702656);
    ushort* Wcb    = (ushort*)(w + 119799808);
    ushort* hp1b   = (ushort*)(w + 123994112);
    ushort* hb     = (ushort*)(w + 124256256);   // [64][128][1024] t-indexed
    ushort* d1r    = (ushort*)(w + 141033472);   // [64][128][2048] t-indexed
    ushort* d2r    = (ushort*)(w + 174587904);   // [64][128][1024] t-indexed
    float*  cvec   = (float*) (w + 191365120);
    uint*   flags  = (uint*)  (w + 191373312);
    // total ws need: 191455232 bytes (fit verified in round 7)

    prep_w<<<dim3(2048), 256, 0, stream>>>(w_ih, w_hh, p_w1, p_w2, mu_w, lv_w,
                                           wihb, whhb, w2b, muwb, lvwb, muwTb, w1h1b, pw1b);
    prep_x<<<dim3(4096), 256, 0, stream>>>(x, hxs_g, hxs_p, masks, oh, ain, hb, hp1b);
    k_cvec<<<dim3(512), 256, 0, stream>>>(p_w1, mu_b, cvec);
    init_flags<<<dim3(80), 256, 0, stream>>>(flags);

    // d1pre (blocked) = Ain @ p_w1^T + b1
    gemm_k<128, 4, false><<<dim3(16, 64), 256, 0, stream>>>(
        ain, 2112, pw1b, 2112, 2112, d1pre, 0, p_b1);
    // gi (blocked) = x @ w_ih^T
    gemm_k<128, 3, true><<<dim3(24, 64), 256, 0, stream>>>(
        x, 1024, wihb, 1024, 1024, gi, 0, nullptr);
    // Wc = W1h1 @ mu_w
    gemm_k<128, 1, false><<<dim3(8, 16), 256, 0, stream>>>(
        w1h1b, 1024, muwTb, 1024, 1024, Wcb, 1024, nullptr);

    persist_k<<<dim3(192), 256, 0, stream>>>(
        whhb, Wcb, w1h1b, w2b, gi, d1pre, hp1b, hb, d1r, d2r,
        masks, b_ih, b_hh, cvec, p_b2, hxs_g, out, flags);

    // p_mu / p_lv from d2r (t-indexed layout == [8192][1024] row-major)
    gemm_k<128, 0, false><<<dim3(8, 64), 256, 0, stream>>>(
        d2r, 1024, muwb, 1024, 1024, out + 8519680, 1024, mu_b);
    gemm_k<128, 0, false><<<dim3(8, 64), 256, 0, stream>>>(
        d2r, 1024, lvwb, 1024, 1024, out + 16908288, 1024, lv_b);

    k_tail<<<dim3(1536), 256, 0, stream>>>(out, x);
}